// Round 21
// baseline (276.217 us; speedup 1.0000x reference)
//
#include <hip/hip_runtime.h>
#include <hip/hip_bf16.h>
#include <stdint.h>

// SelfAttn1D MFMA pipeline v11: v7 with DOUBLED pv regions (256-key tiles,
// 8 barriers/block instead of 16; identical per-point live set to v7).
// All inputs fp32, output fp32.
#define B_SZ 8
#define C_SZ 1024
#define L_SZ 2048
#define D_SZ 128
#define LOG2E 1.44269504088896f

typedef const float* __restrict__ fpp;
typedef __hip_bfloat16 bf16;
typedef short s8v __attribute__((ext_vector_type(8)));   // 8 bf16 (4 VGPR)
typedef float f4v __attribute__((ext_vector_type(4)));   // MFMA C/D

#define MFMA __builtin_amdgcn_mfma_f32_16x16x32_bf16

#define GLOAD16(gp, lp) __builtin_amdgcn_global_load_lds(                  \
    (const __attribute__((address_space(1))) void*)(gp),                   \
    (__attribute__((address_space(3))) void*)(lp), 16, 0, 0)

// ---------------------------------------------------------------------------
__global__ __launch_bounds__(256) void prep_kernel(
    fpp Wq, fpp Wk, fpp Wv, fpp bq, fpp bk, fpp bv,
    bf16* __restrict__ Wcat, float* __restrict__ bcat) {
  const int bidx = blockIdx.x;
  if (bidx < 1280) {
    fpp src; float scale = 1.0f;
    if (bidx < 128)      { src = Wq + (size_t)bidx * C_SZ; scale = LOG2E; }
    else if (bidx < 256) { src = Wk + (size_t)(bidx - 128) * C_SZ; }
    else                 { src = Wv + (size_t)(bidx - 256) * C_SZ; }
    const float4 v = reinterpret_cast<const float4*>(src)[threadIdx.x];
    bf16 o[4] = {__float2bfloat16(v.x * scale), __float2bfloat16(v.y * scale),
                 __float2bfloat16(v.z * scale), __float2bfloat16(v.w * scale)};
    reinterpret_cast<uint2*>(Wcat + (size_t)bidx * C_SZ)[threadIdx.x] =
        *reinterpret_cast<uint2*>(o);
  } else {
    const int i = (bidx - 1280) * 256 + threadIdx.x;
    if (i < 128)        bcat[i] = bq[i] * LOG2E;
    else if (i < 256)   bcat[i] = bk[i - 128];
    else if (i < 1280)  bcat[i] = bv[i - 256];
  }
}

// ---------------------------------------------------------------------------
__global__ __launch_bounds__(256) void transpose_kernel(fpp x, bf16* __restrict__ xT) {
  const int b  = blockIdx.z;
  const int l0 = blockIdx.x * 32;
  const int c0 = blockIdx.y * 32;
  __shared__ float T[32][33];
  const int t = threadIdx.x;
  const int r  = t >> 3;
  const int cg = (t & 7) * 4;
  const float4 v = *reinterpret_cast<const float4*>(
      x + ((size_t)b * C_SZ + c0 + r) * L_SZ + l0 + cg);
  T[r][cg + 0] = v.x; T[r][cg + 1] = v.y; T[r][cg + 2] = v.z; T[r][cg + 3] = v.w;
  __syncthreads();
  bf16 o[4];
#pragma unroll
  for (int i = 0; i < 4; ++i) o[i] = __float2bfloat16(T[cg + i][r]);
  *reinterpret_cast<uint2*>(
      xT + ((size_t)b * L_SZ + l0 + r) * C_SZ + c0 + cg) = *reinterpret_cast<uint2*>(o);
}

// ---------------------------------------------------------------------------
// proj_kernel (m97-style): unified Q/K/V projection, LDS-staged 128x128 tile.
// ---------------------------------------------------------------------------
__global__ __launch_bounds__(256) void proj_kernel(
    const bf16* __restrict__ xTb, const bf16* __restrict__ Wcat, fpp bcat,
    bf16* __restrict__ Qt, bf16* __restrict__ Kt, bf16* __restrict__ Vt) {
  __shared__ bf16 Als[128 * 64];
  __shared__ bf16 Bls[128 * 64];
  const int bid = blockIdx.x;
  const int tid = threadIdx.x, wid = tid >> 6, lane = tid & 63;
  const int lm = lane & 15, lg = lane >> 4;
  const int wm = wid >> 1, wn = wid & 1;
  const bool isQK = bid < 256;

  const bf16 *Arow, *Brow;
  int m0, n0;
  if (isQK) {
    m0 = (bid & 1) * 128;
    n0 = (bid >> 1) * 128;
    Arow = Wcat; Brow = xTb;
  } else {
    const int v = bid - 256;
    m0 = (v >> 3) * 128;
    n0 = (v & 7) * 128;
    Arow = xTb; Brow = Wcat + (size_t)256 * C_SZ;
  }

  const int srow = lane >> 3;
  const int scol = (lane & 7) * 8;

  f4v acc[4][4] = {};
  for (int k0 = 0; k0 < C_SZ; k0 += 64) {
    __syncthreads();
#pragma unroll
    for (int ch = 0; ch < 4; ++ch) {
      const int chunk = wid * 4 + ch;
      const int row = chunk * 8 + srow;
      GLOAD16(Arow + (size_t)(m0 + row) * C_SZ + k0 + scol, &Als[chunk * 512]);
      GLOAD16(Brow + (size_t)(n0 + row) * C_SZ + k0 + scol, &Bls[chunk * 512]);
    }
    __syncthreads();
#pragma unroll
    for (int kc = 0; kc < 2; ++kc) {
      s8v af[4], bfr[4];
#pragma unroll
      for (int i = 0; i < 4; ++i) {
        af[i]  = *reinterpret_cast<const s8v*>(
            &Als[(wm * 64 + i * 16 + lm) * 64 + kc * 32 + lg * 8]);
        bfr[i] = *reinterpret_cast<const s8v*>(
            &Bls[(wn * 64 + i * 16 + lm) * 64 + kc * 32 + lg * 8]);
      }
#pragma unroll
      for (int a = 0; a < 4; ++a)
#pragma unroll
        for (int bj = 0; bj < 4; ++bj)
          acc[a][bj] = MFMA(af[a], bfr[bj], acc[a][bj], 0, 0, 0);
    }
  }

  if (isQK) {
    bf16* dst = (m0 == 0) ? Qt : Kt;
#pragma unroll
    for (int a = 0; a < 4; ++a) {
      const int d = m0 + wm * 64 + a * 16 + lg * 4;
      const int dd = d & 127;
      const float4 bb = *reinterpret_cast<const float4*>(bcat + d);
#pragma unroll
      for (int bj = 0; bj < 4; ++bj) {
        const int gl = n0 + wn * 64 + bj * 16 + lm;
        bf16 o[4] = {__float2bfloat16(acc[a][bj][0] + bb.x),
                     __float2bfloat16(acc[a][bj][1] + bb.y),
                     __float2bfloat16(acc[a][bj][2] + bb.z),
                     __float2bfloat16(acc[a][bj][3] + bb.w)};
        *reinterpret_cast<uint2*>(dst + (size_t)gl * D_SZ + dd) =
            *reinterpret_cast<uint2*>(o);
      }
    }
  } else {
#pragma unroll
    for (int a = 0; a < 4; ++a) {
      const int gl = m0 + wm * 64 + a * 16 + lg * 4;
      const int b = gl >> 11, l = gl & 2047;
#pragma unroll
      for (int bj = 0; bj < 4; ++bj) {
        const int c = n0 + wn * 64 + bj * 16 + lm;
        const float bvc = bcat[256 + c];
        bf16 o[4] = {__float2bfloat16(acc[a][bj][0] + bvc),
                     __float2bfloat16(acc[a][bj][1] + bvc),
                     __float2bfloat16(acc[a][bj][2] + bvc),
                     __float2bfloat16(acc[a][bj][3] + bvc)};
        *reinterpret_cast<uint2*>(Vt + ((size_t)b * C_SZ + c) * L_SZ + l) =
            *reinterpret_cast<uint2*>(o);
      }
    }
  }
}

// ---------------------------------------------------------------------------
// pv_kernel v11: 8 waves, 64q x 1024c per block, 256-key regions (2 K-tiles
// per barrier), grid = b x qt. Wave w: QK for keys w*16 of each 128-key half;
// PV for channels w*128..+128. P (64x256) staged per region in swizzled LDS
// (2 slots x 32 KB); ONE barrier per region (8 total in main loop).
// Ordering is strictly v7 (no rotation): live set identical to v7.
// ---------------------------------------------------------------------------
__global__ __launch_bounds__(512, 2) void pv_kernel(
    const bf16* __restrict__ Qt, const bf16* __restrict__ Kt,
    const bf16* __restrict__ Vt,
    fpp x, fpp gamma, float* __restrict__ out) {
  const int gid = blockIdx.x;
  const int b  = gid & 7;               // XCD-affine batch
  const int qt = gid >> 3;
  const int j0 = qt * 64;
  const int tid = threadIdx.x, wid = tid >> 6, lane = tid & 63;
  const int lm = lane & 15, lg = lane >> 4;

  __shared__ bf16 Qlds[64][128];        // 16 KB, swizzled
  __shared__ bf16 Plds[2][64][256];     // 64 KB, swizzled, 512-B rows
  __shared__ float lred[8][4][16];
  __shared__ float linv_lds[64];
  char* const Qbase = (char*)&Qlds[0][0];
  char* const Pbase = (char*)&Plds[0][0][0];

  const int swz = (lm & 7) << 4;

  // ---- stage Q (64 x 256 B) into swizzled LDS: 512 threads x 32 B ----
  {
    const int r  = tid >> 3;
    const int cb = (tid & 7) * 32;
    const bf16* src = Qt + ((size_t)b * L_SZ + j0 + r) * D_SZ + cb / 2;
    const int m = (r & 7) << 4;
    *reinterpret_cast<s8v*>(Qbase + r * 256 + (cb ^ m)) =
        *reinterpret_cast<const s8v*>(src);
    *reinterpret_cast<s8v*>(Qbase + r * 256 + ((cb + 16) ^ m)) =
        *reinterpret_cast<const s8v*>(src + 8);
  }

  f4v acc[4][8] = {};                   // [mq][nt] -> 64q x 128c per wave
  float lsum[4] = {0.f, 0.f, 0.f, 0.f};
  s8v kreg[4];
  s8v va[8], vb[8];
  const bf16* Kbase = Kt + (size_t)b * L_SZ * D_SZ;
  const bf16* Vbase = Vt + ((size_t)b * C_SZ + wid * 128) * L_SZ;

#define LOADK(KOFF)                                                            \
  _Pragma("unroll") for (int dc = 0; dc < 4; ++dc)                             \
    kreg[dc] = *reinterpret_cast<const s8v*>(                                  \
        Kbase + (size_t)((KOFF) + wid * 16 + lm) * D_SZ + dc * 32 + lg * 8);

#define QK_EXP_WRITE(PDST, HALFB)                                              \
  {                                                                            \
    f4v s[4] = {};                                                             \
    _Pragma("unroll") for (int dc = 0; dc < 4; ++dc) {                         \
      _Pragma("unroll") for (int nq = 0; nq < 4; ++nq) {                       \
        const int row = nq * 16 + lm;                                          \
        const s8v bQf = *reinterpret_cast<const s8v*>(                         \
            Qbase + row * 256 + ((dc * 64 + lg * 16) ^ ((row & 7) << 4)));     \
        s[nq] = MFMA(kreg[dc], bQf, s[nq], 0, 0, 0);                           \
      }                                                                        \
    }                                                                          \
    _Pragma("unroll") for (int nq = 0; nq < 4; ++nq) {                         \
      float p0 = __builtin_amdgcn_exp2f(s[nq][0]);                             \
      float p1 = __builtin_amdgcn_exp2f(s[nq][1]);                             \
      float p2 = __builtin_amdgcn_exp2f(s[nq][2]);                             \
      float p3 = __builtin_amdgcn_exp2f(s[nq][3]);                             \
      lsum[nq] += (p0 + p1) + (p2 + p3);                                       \
      uint2 pw;                                                                \
      pw.x = ((__float_as_uint(p0) + 0x8000u) >> 16) |                         \
             ((__float_as_uint(p1) + 0x8000u) & 0xFFFF0000u);                  \
      pw.y = ((__float_as_uint(p2) + 0x8000u) >> 16) |                         \
             ((__float_as_uint(p3) + 0x8000u) & 0xFFFF0000u);                  \
      *reinterpret_cast<uint2*>(                                               \
          (PDST) + (nq * 16 + lm) * 512 +                                      \
          (((HALFB) + wid * 32 + lg * 8) ^ swz)) = pw;                         \
    }                                                                          \
  }

#define LOADV(BUF, K0, KC)                                                     \
  _Pragma("unroll") for (int nt = 0; nt < 8; ++nt)                             \
    BUF[nt] = *reinterpret_cast<const s8v*>(                                   \
        Vbase + (size_t)(nt * 16 + lm) * L_SZ + (K0) + (KC)*32 + lg * 8);

#define PV_KC(PSRC, KC, CUR, NXT, LAST)                                        \
    {                                                                          \
      if (!(LAST)) { LOADV(NXT, k0, (KC) + 1); }                               \
      s8v aP[4];                                                               \
      _Pragma("unroll") for (int mq = 0; mq < 4; ++mq)                         \
        aP[mq] = *reinterpret_cast<const s8v*>(                                \
            (PSRC) + (mq * 16 + lm) * 512 + (((KC)*64 + lg * 16) ^ swz));      \
      _Pragma("unroll") for (int nt = 0; nt < 8; ++nt)                         \
        _Pragma("unroll") for (int mq = 0; mq < 4; ++mq)                       \
          acc[mq][nt] = MFMA(aP[mq], CUR[nt], acc[mq][nt], 0, 0, 0);           \
    }

  // ---- prologue: K(0) ----
  LOADK(0);
  __syncthreads();                      // Q visible

  for (int m = 0; m < 8; ++m) {
    const int k0 = m * 256;
    char* const Pslot = Pbase + (m & 1) * 32768;

    // V(kc=0) early — hides under both QK halves + exps + barrier
    LOADV(va, k0, 0);

    // ---- QK half A (keys k0 + wid*16), then prefetch K(b) ----
    QK_EXP_WRITE(Pslot, 0);
    LOADK(k0 + 128);
    // ---- QK half B (keys k0+128 + wid*16), then prefetch next region's K --
    QK_EXP_WRITE(Pslot, 256);
    if (m + 1 < 8) { LOADK(k0 + 256); }
    __syncthreads();

    // ---- PV over 256 keys: 8 kc steps, V ping-pong ----
    __builtin_amdgcn_s_setprio(1);
    PV_KC(Pslot, 0, va, vb, false);
    PV_KC(Pslot, 1, vb, va, false);
    PV_KC(Pslot, 2, va, vb, false);
    PV_KC(Pslot, 3, vb, va, false);
    PV_KC(Pslot, 4, va, vb, false);
    PV_KC(Pslot, 5, vb, va, false);
    PV_KC(Pslot, 6, va, vb, false);
    PV_KC(Pslot, 7, vb, va, true);
    __builtin_amdgcn_s_setprio(0);
  }
#undef PV_KC
#undef LOADV
#undef QK_EXP_WRITE
#undef LOADK

  // ---- l reduction: over lg (shfl) then over 8 waves (LDS) ----
#pragma unroll
  for (int nq = 0; nq < 4; ++nq) {
    lsum[nq] += __shfl_xor(lsum[nq], 16);
    lsum[nq] += __shfl_xor(lsum[nq], 32);
  }
  if (lg == 0) {
#pragma unroll
    for (int nq = 0; nq < 4; ++nq) lred[wid][nq][lm] = lsum[nq];
  }
  __syncthreads();
  if (tid < 64) {
    const int nq = tid >> 4, l2 = tid & 15;
    float s = 0.f;
#pragma unroll
    for (int w = 0; w < 8; ++w) s += lred[w][nq][l2];
    linv_lds[tid] = 1.0f / s;
  }
  __syncthreads();

  // ---- epilogue: out = g * acc * linv[q] + x ----
  const float g = gamma[0];
#pragma unroll
  for (int mq = 0; mq < 4; ++mq) {
    float li[4];
#pragma unroll
    for (int r = 0; r < 4; ++r) li[r] = linv_lds[mq * 16 + lg * 4 + r];
#pragma unroll
    for (int nt = 0; nt < 8; ++nt) {
      const int c = wid * 128 + nt * 16 + lm;
      const int j = j0 + mq * 16 + lg * 4;
      const size_t off = ((size_t)b * C_SZ + c) * L_SZ + j;
      const float4 xv = *reinterpret_cast<const float4*>(x + off);
      float4 o;
      o.x = g * (acc[mq][nt][0] * li[0]) + xv.x;
      o.y = g * (acc[mq][nt][1] * li[1]) + xv.y;
      o.z = g * (acc[mq][nt][2] * li[2]) + xv.z;
      o.w = g * (acc[mq][nt][3] * li[3]) + xv.w;
      *reinterpret_cast<float4*>(out + off) = o;
    }
  }
}

// ---------------------------------------------------------------------------
extern "C" void kernel_launch(void* const* d_in, const int* in_sizes, int n_in,
                              void* d_out, int out_size, void* d_ws,
                              size_t ws_size, hipStream_t stream) {
  fpp x     = (fpp)d_in[0];
  fpp Wq    = (fpp)d_in[1];
  fpp bq    = (fpp)d_in[2];
  fpp Wk    = (fpp)d_in[3];
  fpp bk    = (fpp)d_in[4];
  fpp Wv    = (fpp)d_in[5];
  fpp bv    = (fpp)d_in[6];
  fpp gamma = (fpp)d_in[7];
  float* out = (float*)d_out;

  bf16* xTb  = (bf16*)d_out;                                 // 32 MiB scratch
  bf16* Wcat = xTb + (size_t)B_SZ * L_SZ * C_SZ;             // 2.5 MiB
  bf16* Qt = (bf16*)d_ws;                                    // 4 MiB
  bf16* Kt = Qt + (size_t)B_SZ * L_SZ * D_SZ;                // 4 MiB
  bf16* Vt = Kt + (size_t)B_SZ * L_SZ * D_SZ;                // 32 MiB
  float* bcat = (float*)(Vt + (size_t)B_SZ * C_SZ * L_SZ);   // 5 KiB

  const dim3 blk(256);
  prep_kernel<<<dim3(1285), blk, 0, stream>>>(Wq, Wk, Wv, bq, bk, bv, Wcat, bcat);
  transpose_kernel<<<dim3(L_SZ / 32, C_SZ / 32, B_SZ), blk, 0, stream>>>(x, xTb);
  proj_kernel<<<dim3(256 + 1024), blk, 0, stream>>>(xTb, Wcat, bcat, Qt, Kt, Vt);
  pv_kernel<<<dim3(B_SZ * (L_SZ / 64)), dim3(512), 0, stream>>>(
      Qt, Kt, Vt, x, gamma, out);
}

// Round 22
// 263.220 us; speedup vs baseline: 1.0494x; 1.0494x over previous
//
#include <hip/hip_runtime.h>
#include <hip/hip_bf16.h>
#include <stdint.h>

// SelfAttn1D MFMA pipeline — FINAL (= round-15/20 v7, best measured: 264 µs).
// m97-style unified QKV projection + 8-wave pv (64q x 1024c/block, zero QK
// redundancy, 1 barrier/tile, swizzled P/Q LDS, K/V reg prefetch).
// All inputs fp32, output fp32. v8/v8.1/v9/v10/v11 restructurings all
// regressed (256 regs/wave caps occupancy at 2 waves/SIMD; v7's 128-key
// alternation is the best latency-hiding found). Local optimum of family.
#define B_SZ 8
#define C_SZ 1024
#define L_SZ 2048
#define D_SZ 128
#define LOG2E 1.44269504088896f

typedef const float* __restrict__ fpp;
typedef __hip_bfloat16 bf16;
typedef short s8v __attribute__((ext_vector_type(8)));   // 8 bf16 (4 VGPR)
typedef float f4v __attribute__((ext_vector_type(4)));   // MFMA C/D

#define MFMA __builtin_amdgcn_mfma_f32_16x16x32_bf16

#define GLOAD16(gp, lp) __builtin_amdgcn_global_load_lds(                  \
    (const __attribute__((address_space(1))) void*)(gp),                   \
    (__attribute__((address_space(3))) void*)(lp), 16, 0, 0)

// ---------------------------------------------------------------------------
__global__ __launch_bounds__(256) void prep_kernel(
    fpp Wq, fpp Wk, fpp Wv, fpp bq, fpp bk, fpp bv,
    bf16* __restrict__ Wcat, float* __restrict__ bcat) {
  const int bidx = blockIdx.x;
  if (bidx < 1280) {
    fpp src; float scale = 1.0f;
    if (bidx < 128)      { src = Wq + (size_t)bidx * C_SZ; scale = LOG2E; }
    else if (bidx < 256) { src = Wk + (size_t)(bidx - 128) * C_SZ; }
    else                 { src = Wv + (size_t)(bidx - 256) * C_SZ; }
    const float4 v = reinterpret_cast<const float4*>(src)[threadIdx.x];
    bf16 o[4] = {__float2bfloat16(v.x * scale), __float2bfloat16(v.y * scale),
                 __float2bfloat16(v.z * scale), __float2bfloat16(v.w * scale)};
    reinterpret_cast<uint2*>(Wcat + (size_t)bidx * C_SZ)[threadIdx.x] =
        *reinterpret_cast<uint2*>(o);
  } else {
    const int i = (bidx - 1280) * 256 + threadIdx.x;
    if (i < 128)        bcat[i] = bq[i] * LOG2E;
    else if (i < 256)   bcat[i] = bk[i - 128];
    else if (i < 1280)  bcat[i] = bv[i - 256];
  }
}

// ---------------------------------------------------------------------------
__global__ __launch_bounds__(256) void transpose_kernel(fpp x, bf16* __restrict__ xT) {
  const int b  = blockIdx.z;
  const int l0 = blockIdx.x * 32;
  const int c0 = blockIdx.y * 32;
  __shared__ float T[32][33];
  const int t = threadIdx.x;
  const int r  = t >> 3;
  const int cg = (t & 7) * 4;
  const float4 v = *reinterpret_cast<const float4*>(
      x + ((size_t)b * C_SZ + c0 + r) * L_SZ + l0 + cg);
  T[r][cg + 0] = v.x; T[r][cg + 1] = v.y; T[r][cg + 2] = v.z; T[r][cg + 3] = v.w;
  __syncthreads();
  bf16 o[4];
#pragma unroll
  for (int i = 0; i < 4; ++i) o[i] = __float2bfloat16(T[cg + i][r]);
  *reinterpret_cast<uint2*>(
      xT + ((size_t)b * L_SZ + l0 + r) * C_SZ + c0 + cg) = *reinterpret_cast<uint2*>(o);
}

// ---------------------------------------------------------------------------
// proj_kernel (m97-style): unified Q/K/V projection, LDS-staged 128x128 tile.
// ---------------------------------------------------------------------------
__global__ __launch_bounds__(256) void proj_kernel(
    const bf16* __restrict__ xTb, const bf16* __restrict__ Wcat, fpp bcat,
    bf16* __restrict__ Qt, bf16* __restrict__ Kt, bf16* __restrict__ Vt) {
  __shared__ bf16 Als[128 * 64];
  __shared__ bf16 Bls[128 * 64];
  const int bid = blockIdx.x;
  const int tid = threadIdx.x, wid = tid >> 6, lane = tid & 63;
  const int lm = lane & 15, lg = lane >> 4;
  const int wm = wid >> 1, wn = wid & 1;
  const bool isQK = bid < 256;

  const bf16 *Arow, *Brow;
  int m0, n0;
  if (isQK) {
    m0 = (bid & 1) * 128;
    n0 = (bid >> 1) * 128;
    Arow = Wcat; Brow = xTb;
  } else {
    const int v = bid - 256;
    m0 = (v >> 3) * 128;
    n0 = (v & 7) * 128;
    Arow = xTb; Brow = Wcat + (size_t)256 * C_SZ;
  }

  const int srow = lane >> 3;
  const int scol = (lane & 7) * 8;

  f4v acc[4][4] = {};
  for (int k0 = 0; k0 < C_SZ; k0 += 64) {
    __syncthreads();
#pragma unroll
    for (int ch = 0; ch < 4; ++ch) {
      const int chunk = wid * 4 + ch;
      const int row = chunk * 8 + srow;
      GLOAD16(Arow + (size_t)(m0 + row) * C_SZ + k0 + scol, &Als[chunk * 512]);
      GLOAD16(Brow + (size_t)(n0 + row) * C_SZ + k0 + scol, &Bls[chunk * 512]);
    }
    __syncthreads();
#pragma unroll
    for (int kc = 0; kc < 2; ++kc) {
      s8v af[4], bfr[4];
#pragma unroll
      for (int i = 0; i < 4; ++i) {
        af[i]  = *reinterpret_cast<const s8v*>(
            &Als[(wm * 64 + i * 16 + lm) * 64 + kc * 32 + lg * 8]);
        bfr[i] = *reinterpret_cast<const s8v*>(
            &Bls[(wn * 64 + i * 16 + lm) * 64 + kc * 32 + lg * 8]);
      }
#pragma unroll
      for (int a = 0; a < 4; ++a)
#pragma unroll
        for (int bj = 0; bj < 4; ++bj)
          acc[a][bj] = MFMA(af[a], bfr[bj], acc[a][bj], 0, 0, 0);
    }
  }

  if (isQK) {
    bf16* dst = (m0 == 0) ? Qt : Kt;
#pragma unroll
    for (int a = 0; a < 4; ++a) {
      const int d = m0 + wm * 64 + a * 16 + lg * 4;
      const int dd = d & 127;
      const float4 bb = *reinterpret_cast<const float4*>(bcat + d);
#pragma unroll
      for (int bj = 0; bj < 4; ++bj) {
        const int gl = n0 + wn * 64 + bj * 16 + lm;
        bf16 o[4] = {__float2bfloat16(acc[a][bj][0] + bb.x),
                     __float2bfloat16(acc[a][bj][1] + bb.y),
                     __float2bfloat16(acc[a][bj][2] + bb.z),
                     __float2bfloat16(acc[a][bj][3] + bb.w)};
        *reinterpret_cast<uint2*>(dst + (size_t)gl * D_SZ + dd) =
            *reinterpret_cast<uint2*>(o);
      }
    }
  } else {
#pragma unroll
    for (int a = 0; a < 4; ++a) {
      const int gl = m0 + wm * 64 + a * 16 + lg * 4;
      const int b = gl >> 11, l = gl & 2047;
#pragma unroll
      for (int bj = 0; bj < 4; ++bj) {
        const int c = n0 + wn * 64 + bj * 16 + lm;
        const float bvc = bcat[256 + c];
        bf16 o[4] = {__float2bfloat16(acc[a][bj][0] + bvc),
                     __float2bfloat16(acc[a][bj][1] + bvc),
                     __float2bfloat16(acc[a][bj][2] + bvc),
                     __float2bfloat16(acc[a][bj][3] + bvc)};
        *reinterpret_cast<uint2*>(Vt + ((size_t)b * C_SZ + c) * L_SZ + l) =
            *reinterpret_cast<uint2*>(o);
      }
    }
  }
}

// ---------------------------------------------------------------------------
// pv_kernel v7: 8 waves, 64q x 1024c per block, 128-key tiles, grid = b x qt.
// Wave w: QK for keys w*16..+16 (all 64 q); PV for channels w*128..+128.
// P (64x128) staged once per tile in swizzled LDS; 1 barrier/tile.
// V kc-level double-buffer issued ahead of the barrier; K(n+1) after QK(n).
// ---------------------------------------------------------------------------
__global__ __launch_bounds__(512, 2) void pv_kernel(
    const bf16* __restrict__ Qt, const bf16* __restrict__ Kt,
    const bf16* __restrict__ Vt,
    fpp x, fpp gamma, float* __restrict__ out) {
  const int gid = blockIdx.x;
  const int b  = gid & 7;               // XCD-affine batch
  const int qt = gid >> 3;
  const int j0 = qt * 64;
  const int tid = threadIdx.x, wid = tid >> 6, lane = tid & 63;
  const int lm = lane & 15, lg = lane >> 4;

  __shared__ bf16 Qlds[64][128];        // 16 KB, swizzled
  __shared__ bf16 Plds[2][64][128];     // 32 KB, swizzled
  __shared__ float lred[8][4][16];
  __shared__ float linv_lds[64];
  char* const Qbase = (char*)&Qlds[0][0];
  char* const Pbase = (char*)&Plds[0][0][0];

  const int swz = (lm & 7) << 4;

  // ---- stage Q (64 x 256 B) into swizzled LDS: 512 threads x 32 B ----
  {
    const int r  = tid >> 3;
    const int cb = (tid & 7) * 32;
    const bf16* src = Qt + ((size_t)b * L_SZ + j0 + r) * D_SZ + cb / 2;
    const int m = (r & 7) << 4;
    *reinterpret_cast<s8v*>(Qbase + r * 256 + (cb ^ m)) =
        *reinterpret_cast<const s8v*>(src);
    *reinterpret_cast<s8v*>(Qbase + r * 256 + ((cb + 16) ^ m)) =
        *reinterpret_cast<const s8v*>(src + 8);
  }

  f4v acc[4][8] = {};                   // [mq][nt] -> 64q x 128c per wave
  float lsum[4] = {0.f, 0.f, 0.f, 0.f};
  s8v kreg[4];
  s8v va[8], vb[8];
  const bf16* Kbase = Kt + (size_t)b * L_SZ * D_SZ;
  const bf16* Vbase = Vt + ((size_t)b * C_SZ + wid * 128) * L_SZ;

  // K(0) prologue
#pragma unroll
  for (int dc = 0; dc < 4; ++dc)
    kreg[dc] = *reinterpret_cast<const s8v*>(
        Kbase + (size_t)(wid * 16 + lm) * D_SZ + dc * 32 + lg * 8);
  __syncthreads();                      // Q visible

#define LOADV(BUF, K0, KC)                                                     \
  _Pragma("unroll") for (int nt = 0; nt < 8; ++nt)                             \
    BUF[nt] = *reinterpret_cast<const s8v*>(                                   \
        Vbase + (size_t)(nt * 16 + lm) * L_SZ + (K0) + (KC)*32 + lg * 8);

  for (int n = 0; n < 16; ++n) {
    const int k0 = n * 128;
    char* const Pslot = Pbase + (n & 1) * 16384;

    // V(kc=0) early — independent of P, hides under QK+exp+barrier
    LOADV(va, k0, 0);

    // ---- QK(n): A = K(regs), B = Q(swizzled LDS) ----
    f4v s[4] = {};
#pragma unroll
    for (int dc = 0; dc < 4; ++dc) {
#pragma unroll
      for (int nq = 0; nq < 4; ++nq) {
        const int row = nq * 16 + lm;
        const s8v bQf = *reinterpret_cast<const s8v*>(
            Qbase + row * 256 + ((dc * 64 + lg * 16) ^ ((row & 7) << 4)));
        s[nq] = MFMA(kreg[dc], bQf, s[nq], 0, 0, 0);
      }
    }
    // K(n+1) prefetch (kreg consumed by QK(n))
    if (n + 1 < 16) {
#pragma unroll
      for (int dc = 0; dc < 4; ++dc)
        kreg[dc] = *reinterpret_cast<const s8v*>(
            Kbase + (size_t)(k0 + 128 + wid * 16 + lm) * D_SZ + dc * 32 + lg * 8);
    }
    // ---- exp2, fast bf16 pack, row sums, swizzled P write ----
#pragma unroll
    for (int nq = 0; nq < 4; ++nq) {
      float p0 = __builtin_amdgcn_exp2f(s[nq][0]);
      float p1 = __builtin_amdgcn_exp2f(s[nq][1]);
      float p2 = __builtin_amdgcn_exp2f(s[nq][2]);
      float p3 = __builtin_amdgcn_exp2f(s[nq][3]);
      lsum[nq] += (p0 + p1) + (p2 + p3);
      uint2 pw;
      pw.x = ((__float_as_uint(p0) + 0x8000u) >> 16) |
             ((__float_as_uint(p1) + 0x8000u) & 0xFFFF0000u);
      pw.y = ((__float_as_uint(p2) + 0x8000u) >> 16) |
             ((__float_as_uint(p3) + 0x8000u) & 0xFFFF0000u);
      *reinterpret_cast<uint2*>(
          Pslot + (nq * 16 + lm) * 256 + ((wid * 32 + lg * 8) ^ swz)) = pw;
    }
    __syncthreads();

    // ---- PV(n): A = P(swizzled LDS), B = V(dbuf regs) ----
    __builtin_amdgcn_s_setprio(1);
#define PV_KC(KC, CUR, NXT, LAST)                                              \
    {                                                                          \
      if (!(LAST)) { LOADV(NXT, k0, (KC) + 1); }                               \
      s8v aP[4];                                                               \
      _Pragma("unroll") for (int mq = 0; mq < 4; ++mq)                         \
        aP[mq] = *reinterpret_cast<const s8v*>(                                \
            Pslot + (mq * 16 + lm) * 256 + (((KC)*64 + lg * 16) ^ swz));       \
      _Pragma("unroll") for (int nt = 0; nt < 8; ++nt)                         \
        _Pragma("unroll") for (int mq = 0; mq < 4; ++mq)                       \
          acc[mq][nt] = MFMA(aP[mq], CUR[nt], acc[mq][nt], 0, 0, 0);           \
    }
    PV_KC(0, va, vb, false);
    PV_KC(1, vb, va, false);
    PV_KC(2, va, vb, false);
    PV_KC(3, vb, va, true);
#undef PV_KC
    __builtin_amdgcn_s_setprio(0);
  }
#undef LOADV

  // ---- l reduction: over lg (shfl) then over 8 waves (LDS) ----
#pragma unroll
  for (int nq = 0; nq < 4; ++nq) {
    lsum[nq] += __shfl_xor(lsum[nq], 16);
    lsum[nq] += __shfl_xor(lsum[nq], 32);
  }
  if (lg == 0) {
#pragma unroll
    for (int nq = 0; nq < 4; ++nq) lred[wid][nq][lm] = lsum[nq];
  }
  __syncthreads();
  if (tid < 64) {
    const int nq = tid >> 4, l2 = tid & 15;
    float s = 0.f;
#pragma unroll
    for (int w = 0; w < 8; ++w) s += lred[w][nq][l2];
    linv_lds[tid] = 1.0f / s;
  }
  __syncthreads();

  // ---- epilogue: out = g * acc * linv[q] + x ----
  const float g = gamma[0];
#pragma unroll
  for (int mq = 0; mq < 4; ++mq) {
    float li[4];
#pragma unroll
    for (int r = 0; r < 4; ++r) li[r] = linv_lds[mq * 16 + lg * 4 + r];
#pragma unroll
    for (int nt = 0; nt < 8; ++nt) {
      const int c = wid * 128 + nt * 16 + lm;
      const int j = j0 + mq * 16 + lg * 4;
      const size_t off = ((size_t)b * C_SZ + c) * L_SZ + j;
      const float4 xv = *reinterpret_cast<const float4*>(x + off);
      float4 o;
      o.x = g * (acc[mq][nt][0] * li[0]) + xv.x;
      o.y = g * (acc[mq][nt][1] * li[1]) + xv.y;
      o.z = g * (acc[mq][nt][2] * li[2]) + xv.z;
      o.w = g * (acc[mq][nt][3] * li[3]) + xv.w;
      *reinterpret_cast<float4*>(out + off) = o;
    }
  }
}

// ---------------------------------------------------------------------------
extern "C" void kernel_launch(void* const* d_in, const int* in_sizes, int n_in,
                              void* d_out, int out_size, void* d_ws,
                              size_t ws_size, hipStream_t stream) {
  fpp x     = (fpp)d_in[0];
  fpp Wq    = (fpp)d_in[1];
  fpp bq    = (fpp)d_in[2];
  fpp Wk    = (fpp)d_in[3];
  fpp bk    = (fpp)d_in[4];
  fpp Wv    = (fpp)d_in[5];
  fpp bv    = (fpp)d_in[6];
  fpp gamma = (fpp)d_in[7];
  float* out = (float*)d_out;

  bf16* xTb  = (bf16*)d_out;                                 // 32 MiB scratch
  bf16* Wcat = xTb + (size_t)B_SZ * L_SZ * C_SZ;             // 2.5 MiB
  bf16* Qt = (bf16*)d_ws;                                    // 4 MiB
  bf16* Kt = Qt + (size_t)B_SZ * L_SZ * D_SZ;                // 4 MiB
  bf16* Vt = Kt + (size_t)B_SZ * L_SZ * D_SZ;                // 32 MiB
  float* bcat = (float*)(Vt + (size_t)B_SZ * C_SZ * L_SZ);   // 5 KiB

  const dim3 blk(256);
  prep_kernel<<<dim3(1285), blk, 0, stream>>>(Wq, Wk, Wv, bq, bk, bv, Wcat, bcat);
  transpose_kernel<<<dim3(L_SZ / 32, C_SZ / 32, B_SZ), blk, 0, stream>>>(x, xTb);
  proj_kernel<<<dim3(256 + 1024), blk, 0, stream>>>(xTb, Wcat, bcat, Qt, Kt, Vt);
  pv_kernel<<<dim3(B_SZ * (L_SZ / 64)), dim3(512), 0, stream>>>(
      Qt, Kt, Vt, x, gamma, out);
}